// Round 21
// baseline (1145.763 us; speedup 1.0000x reference)
//
#include <hip/hip_runtime.h>
#include <math.h>

#define CIN   16
#define COUT  64
#define H     256
#define W     256
#define OH    254
#define OW    254
#define NTAP  9
#define HWSZ  (H * W)
#define RING  18
#define SROW  136        // f16x8 slots per ring row: 2 cin-halves * 68 px

typedef _Float16 f16x8  __attribute__((ext_vector_type(8)));
typedef float    f32x16 __attribute__((ext_vector_type(16)));

// Raw barrier (no vmcnt drain): global loads stay in flight across it.
#define BARRIER()                                                               \
    __builtin_amdgcn_sched_barrier(0);                                          \
    asm volatile("s_waitcnt lgkmcnt(0)" ::: "memory");                          \
    __builtin_amdgcn_s_barrier();                                               \
    __builtin_amdgcn_sched_barrier(0);

// weight pack: [tap 9][msub 2][lane 64][e 8] fp16; co=(l&31)+32m, cin=8*(l>>5)+e
__global__ void wpack_kernel(const float* __restrict__ w, _Float16* __restrict__ wpk) {
    int idx = blockIdx.x * 256 + threadIdx.x;   // 0..9215
    if (idx >= NTAP * 2 * 64 * 8) return;
    int e = idx & 7, l = (idx >> 3) & 63, m = (idx >> 9) & 1, t = idx >> 10;
    int co  = (l & 31) + 32 * m;
    int cin = 8 * (l >> 5) + e;
    wpk[idx] = (_Float16)w[((co * CIN + cin) * 3 + t / 3) * 3 + (t % 3)];
}

__device__ __forceinline__ float tanh_fast(float v) {
    float e = __expf(2.0f * v);
    return 1.0f - 2.0f * __builtin_amdgcn_rcpf(e + 1.0f);
}
__device__ __forceinline__ float min3f(float a, float b, float c) {
    return fminf(fminf(a, b), c);
}
// keep a ds_read_b128 result live without using it (rule #17)
__device__ __forceinline__ void sinkv(f16x8 v) {
    int4 s = __builtin_bit_cast(int4, v);
    asm volatile("" :: "v"(s.x), "v"(s.y), "v"(s.z), "v"(s.w));
}

// MODE 0: full pipeline. MODE 1: MFMAs removed (reads sunk, acc=bias).
// MODE 2: staging reads from L2-resident dummy (same instr structure).
// MODE 3: no global loads in the loop (pure LDS->MFMA->epilogue).
template<int MODE>
__global__ __launch_bounds__(256, 2) void kdiag(
        const float* __restrict__ x, const f16x8* __restrict__ wpk,
        const float* __restrict__ bias, float* __restrict__ outp,
        float* __restrict__ dumo, const float* __restrict__ dsrc,
        int npass, int toReal) {
    __shared__ f16x8 ring[RING * SROW];
    __shared__ float bias_lds[64];

    const int tid  = threadIdx.x;
    const int lane = tid & 63;

    int bid = blockIdx.x;
    int nb  = (bid & 7) * 64 + (bid >> 3);
    const int img  = nb >> 3;
    const int rem  = nb & 7;
    const int colb = rem & 3;
    const int half = rem >> 2;
    const int base = 64 * colb;
    const int R0   = 128 * half;
    const int S0   = half ? 2 : 0;             // R0 % 18

    const float* xb = x + (size_t)img * CIN * HWSZ;

    f16x8 wreg[NTAP][2];
#pragma unroll
    for (int t = 0; t < NTAP; ++t)
#pragma unroll
        for (int m = 0; m < 2; ++m)
            wreg[t][m] = wpk[(t * 2 + m) * 64 + lane];

    if (tid < 64) {
        int q = tid & 15, m = (tid >> 4) & 1, g = tid >> 5;
        bias_lds[tid] = bias[(q & 3) + 8 * (q >> 2) + 4 * g + 32 * m];
    }

    int r8[3], gq[3], gx[3], wof[3];
#pragma unroll
    for (int k = 0; k < 3; ++k) {
        int u  = tid + 256 * k;
        r8[k]  = u / 68;
        int r2 = u - 68 * r8[k];
        int g  = (r2 >= 34) ? 1 : 0;
        int p  = r2 - 34 * g;
        int px = base + 2 * p; if (px > 254) px = 254;
        gq[k]  = g;
        gx[k]  = px;
        wof[k] = g * 68 + 2 * p;
    }
    const bool act2 = (tid < 32);

    const int wv  = tid >> 6;
    const int s   = wv & 1;
    const int rg  = wv >> 1;
    const int l31 = lane & 31;
    const int g2  = lane >> 5;
    const int foff = g2 * 68 + 32 * s + l31;
    const int opx  = base + 32 * s + l31;
    const size_t obase = (size_t)img * OH * OW;
    const f32x16* bp = (const f32x16*)(bias_lds + g2 * 32);

    float2 vA[8], vB[8], vC[8];

#define PLOADK(k, rowAbs, vv)                                                   \
    {                                                                           \
        int gr = (rowAbs); if (gr > 255) gr = 255;                              \
        if constexpr (MODE == 2) {                                              \
            _Pragma("unroll")                                                   \
            for (int cc = 0; cc < 8; ++cc) {                                    \
                int idx_ = (8 * gq[k] + cc) * HWSZ + gr * W + gx[k];            \
                vv[cc] = *(const float2*)(dsrc + (idx_ & 8190));                \
            }                                                                   \
        } else {                                                                \
            const float* gp = xb + (size_t)(8 * gq[k]) * HWSZ + (size_t)gr * W + gx[k]; \
            _Pragma("unroll")                                                   \
            for (int cc = 0; cc < 8; ++cc)                                      \
                vv[cc] = *(const float2*)(gp + (size_t)cc * HWSZ);              \
        }                                                                       \
    }

#define PWRITEK(k, slot, vv)                                                    \
    {                                                                           \
        f16x8 q0, q1;                                                           \
        _Pragma("unroll")                                                       \
        for (int cc = 0; cc < 8; ++cc) { q0[cc] = (_Float16)vv[cc].x;           \
                                         q1[cc] = (_Float16)vv[cc].y; }         \
        const int ad = (slot) * SROW + wof[k];                                  \
        ring[ad]     = q0;                                                      \
        ring[ad + 1] = q1;                                                      \
    }

#pragma unroll 1
    for (int pass = 0; pass < npass; ++pass) {
        float* op = (pass == 0) ? outp : dumo;

        // ---- prologue: stage rows R0..R0+9 ----
#pragma unroll
        for (int k = 0; k < 3; ++k) {
            int u = tid + 256 * k;
            if (k == 2 && tid >= 168) break;
            int r10 = u / 68;
            int r2  = u - 68 * r10;
            int g   = (r2 >= 34) ? 1 : 0;
            int p   = r2 - 34 * g;
            int px  = base + 2 * p; if (px > 254) px = 254;
            float2 vm[8];
            if constexpr (MODE == 2) {
#pragma unroll
                for (int cc = 0; cc < 8; ++cc) {
                    int idx_ = (8 * g + cc) * HWSZ + (R0 + r10) * W + px;
                    vm[cc] = *(const float2*)(dsrc + (idx_ & 8190));
                }
            } else {
                const float* gp = xb + (size_t)(8 * g) * HWSZ + (size_t)(R0 + r10) * W + px;
#pragma unroll
                for (int cc = 0; cc < 8; ++cc) vm[cc] = *(const float2*)(gp + (size_t)cc * HWSZ);
            }
            f16x8 q0, q1;
#pragma unroll
            for (int cc = 0; cc < 8; ++cc) { q0[cc] = (_Float16)vm[cc].x;
                                             q1[cc] = (_Float16)vm[cc].y; }
            const int ad = (S0 + r10) * SROW + g * 68 + 2 * p;
            ring[ad]     = q0;
            ring[ad + 1] = q1;
        }

        if constexpr (MODE != 3) {
            PLOADK(0, R0 + 10 + r8[0], vA)
            PLOADK(1, R0 + 10 + r8[1], vB)
            if (act2) PLOADK(2, R0 + 10 + r8[2], vC)
        }
        BARRIER()

        int slot0 = S0;
#pragma unroll 1
        for (int t = 0; t < 16; ++t) {
            const int row0 = R0 + 8 * t;

#pragma unroll
            for (int c = 0; c < 2; ++c) {
                const int rowoff = 4 * rg + 2 * c;
                f32x16 cb0 = bp[0], cb1 = bp[1];
                f32x16 acc[2][2];
                if constexpr (MODE == 1) {
#pragma unroll
                    for (int ro = 0; ro < 2; ++ro) { acc[ro][0] = cb0; acc[ro][1] = cb1; }
                }
#pragma unroll
                for (int dd = 0; dd < 4; ++dd) {
                    int sl = slot0 + rowoff + dd; if (sl >= RING) sl -= RING;
                    const f16x8* rp = ring + sl * SROW + foff;
                    f16x8 f0 = rp[0], f1 = rp[1], f2 = rp[2];
                    if constexpr (MODE == 1) {
                        sinkv(f0); sinkv(f1); sinkv(f2);
                    } else {
#pragma unroll
                        for (int kw = 0; kw < 3; ++kw) {
                            f16x8 ff = (kw == 0) ? f0 : (kw == 1) ? f1 : f2;
#pragma unroll
                            for (int ro = 0; ro < 2; ++ro) {
                                const int kh = dd - ro;
                                if (kh < 0 || kh > 2) continue;
#pragma unroll
                                for (int m = 0; m < 2; ++m) {
                                    const f32x16& ci = (kh == 0 && kw == 0)
                                                     ? (m == 0 ? cb0 : cb1) : acc[ro][m];
                                    acc[ro][m] = __builtin_amdgcn_mfma_f32_32x32x16_f16(
                                        wreg[kh * 3 + kw][m], ff, ci, 0, 0, 0);
                                }
                            }
                        }
                    }
                }
#pragma unroll
                for (int ro = 0; ro < 2; ++ro) {
                    float mn = fminf(acc[ro][0][0], acc[ro][1][0]);
#pragma unroll
                    for (int q = 1; q < 16; ++q)
                        mn = min3f(acc[ro][0][q], acc[ro][1][q], mn);
                    mn = fminf(mn, __shfl_xor(mn, 32));
                    float t2 = tanh_fast(tanh_fast(mn));
                    const int oh = row0 + rowoff + ro;
                    if (g2 == 0 && oh < OH && opx < OW) {
                        const size_t oidx = obase + (size_t)oh * OW + opx;
                        if (toReal) op[oidx] = t2;
                        else        op[oidx & 0x3FFFFF] = t2;
                    }
                }
            }

            if constexpr (MODE != 3) {
                if (t <= 14) {
                    int sl0 = slot0 + 10 + r8[0]; if (sl0 >= RING) sl0 -= RING;
                    int sl1 = slot0 + 10 + r8[1]; if (sl1 >= RING) sl1 -= RING;
                    PWRITEK(0, sl0, vA)
                    PWRITEK(1, sl1, vB)
                    if (act2) {
                        int sl2 = slot0 + 10 + r8[2]; if (sl2 >= RING) sl2 -= RING;
                        PWRITEK(2, sl2, vC)
                    }
                }
                if (t <= 13) {
                    PLOADK(0, row0 + 18 + r8[0], vA)
                    PLOADK(1, row0 + 18 + r8[1], vB)
                    if (act2) PLOADK(2, row0 + 18 + r8[2], vC)
                }
            }
            BARRIER()
            slot0 += 8; if (slot0 >= RING) slot0 -= RING;
        }
    }
}

extern "C" void kernel_launch(void* const* d_in, const int* in_sizes, int n_in,
                              void* d_out, int out_size, void* d_ws, size_t ws_size,
                              hipStream_t stream) {
    const float* x    = (const float*)d_in[0];
    const float* w    = (const float*)d_in[1];
    const float* bias = (const float*)d_in[2];
    float* out = (float*)d_out;
    _Float16* wpk = (_Float16*)d_ws;                          // [0, 18KB)
    const float* dsrc = (const float*)((char*)d_ws + (64 << 10));  // 32KB window (0xAA poison)
    float* dumo = (float*)((char*)d_ws + (4 << 20));          // 16MB dummy-out window
    const f16x8* wp8 = (const f16x8*)wpk;

    wpack_kernel<<<36, 256, 0, stream>>>(w, wpk);
    // --- diagnostics (outputs to d_ws only) ---
    kdiag<0><<<512, 256, 0, stream>>>(x, wp8, bias, dumo, dumo, dsrc, 2, 0); // anchor
    kdiag<1><<<512, 256, 0, stream>>>(x, wp8, bias, dumo, dumo, dsrc, 6, 0); // no MFMA
    kdiag<2><<<512, 256, 0, stream>>>(x, wp8, bias, dumo, dumo, dsrc, 6, 0); // fake src
    kdiag<3><<<512, 256, 0, stream>>>(x, wp8, bias, dumo, dumo, dsrc, 5, 0); // no staging
    // --- the real kernel (correct d_out) ---
    kdiag<0><<<512, 256, 0, stream>>>(x, wp8, bias, out, dumo, dsrc, 1, 1);
}

// Round 22
// 107.295 us; speedup vs baseline: 10.6786x; 10.6786x over previous
//
#include <hip/hip_runtime.h>
#include <math.h>
#include <stdint.h>

#define CIN   16
#define COUT  64
#define H     256
#define W     256
#define OH    254
#define OW    254
#define NTAP  9
#define HWSZ  (H * W)
#define RING  15
#define SLOTF 1088        // floats per slot: [16 cin][64 px] main + [16][4] halo

typedef _Float16 f16x8  __attribute__((ext_vector_type(8)));
typedef float    f32x16 __attribute__((ext_vector_type(16)));

// Zero-VGPR async global->LDS (compiler cannot sink it): dword per lane,
// dest = uniform base + lane*4.
#define GLL(gp, lp)                                                             \
    __builtin_amdgcn_global_load_lds(                                           \
        (const __attribute__((address_space(1))) uint32_t*)(gp),                \
        (__attribute__((address_space(3))) uint32_t*)(lp), 4, 0, 0)

// weight pack: [tap 9][msub 2][lane 64][e 8] fp16; co=(l&31)+32m, cin=8*(l>>5)+e
__global__ void wpack_kernel(const float* __restrict__ w, _Float16* __restrict__ wpk) {
    int idx = blockIdx.x * 256 + threadIdx.x;   // 0..9215
    if (idx >= NTAP * 2 * 64 * 8) return;
    int e = idx & 7, l = (idx >> 3) & 63, m = (idx >> 9) & 1, t = idx >> 10;
    int co  = (l & 31) + 32 * m;
    int cin = 8 * (l >> 5) + e;
    wpk[idx] = (_Float16)w[((co * CIN + cin) * 3 + t / 3) * 3 + (t % 3)];
}

__device__ __forceinline__ float tanh_fast(float v) {
    float e = __expf(2.0f * v);
    return 1.0f - 2.0f * __builtin_amdgcn_rcpf(e + 1.0f);
}
__device__ __forceinline__ float min3f(float a, float b, float c) {
    return fminf(fminf(a, b), c);   // clang fuses to v_min3_f32
}

// 256 thr = 4 waves; block = 64-px col x 128-row half; 2 blocks/CU.
// Wave w loads (via global_load_lds) and computes rows == w (mod 4).
// Per iter: vmcnt(2) [waits only I(t-1)] -> raw barrier -> issue row t+8
// -> pure-LDS compute (f32 frags, cvt at consumer) -> epilogue.
__global__ __launch_bounds__(256, 2) void conv_gll_kernel(
        const float* __restrict__ x, const f16x8* __restrict__ wpk,
        const float* __restrict__ bias, float* __restrict__ out) {
    __shared__ float ring[RING * SLOTF];   // 65,280 B

    const int tid  = threadIdx.x;
    const int lane = tid & 63;
    const int wv   = tid >> 6;

    int bid = blockIdx.x;
    int nb  = (bid & 7) * 64 + (bid >> 3);     // 512 = 8*64 bijective XCD swizzle
    const int img  = nb >> 3;
    const int rem  = nb & 7;
    const int colb = rem & 3;                  // 64-px column
    const int half = rem >> 2;                 // 128-row half
    const int base = colb * 64;
    const int R0   = half * 128;

    const float* xb = x + (size_t)img * CIN * HWSZ;

    // ---- weights: full 64 cout -> 72 VGPRs ----
    f16x8 wreg[NTAP][2];
#pragma unroll
    for (int t = 0; t < NTAP; ++t)
#pragma unroll
        for (int m = 0; m < 2; ++m)
            wreg[t][m] = wpk[(t * 2 + m) * 64 + lane];

    const int l31 = lane & 31;
    const int g2  = lane >> 5;

    // bias C-fragment: col=l31(px), row=(q&3)+8*(q>>2)+4*g2+32m (co)
    f32x16 cbias[2];
#pragma unroll
    for (int m = 0; m < 2; ++m)
#pragma unroll
        for (int q = 0; q < 16; ++q)
            cbias[m][q] = bias[(q & 3) + 8 * (q >> 2) + 4 * g2 + 32 * m];

    // issue all 17 GLLs for block-row q (input row R0+q) into slot q%RING
    auto issue_row = [&](int q) {
        int grow = R0 + q; if (grow > 255) grow = 255;
        float* sp = &ring[(q % RING) * SLOTF];
        const float* gs = xb + (size_t)grow * W + base + lane;  // per-lane px
#pragma unroll
        for (int c = 0; c < CIN; ++c)
            GLL(gs + (size_t)c * HWSZ, sp + c * 64);            // uniform dest
        int hpx = base + 64 + (lane & 3); if (hpx > 255) hpx = 255;
        GLL(xb + (size_t)(lane >> 2) * HWSZ + (size_t)grow * W + hpx, sp + 1024);
    };

    // ---- prologue: 2 rows deep per wave (rows w, w+4 in flight) ----
    issue_row(wv);
    issue_row(wv + 4);

    const size_t obase = (size_t)img * OH * OW;

#pragma unroll 1
    for (int t = 0; t < 32; ++t) {
        // wait: only I(t-1) must land (issued a full iteration ago);
        // leaves this iter's pipe work untouched. 2 = this wave's stores.
        asm volatile("s_waitcnt vmcnt(2)" ::: "memory");
        __builtin_amdgcn_sched_barrier(0);
        __builtin_amdgcn_s_barrier();
        __builtin_amdgcn_sched_barrier(0);

        // issue row t+8 immediately (stays in flight through this compute)
        issue_row(4 * t + wv + 8);
        __builtin_amdgcn_sched_barrier(0);

        const int q0 = 4 * t + wv;
        const float* s0 = &ring[((q0    ) % RING) * SLOTF];
        const float* s1 = &ring[((q0 + 1) % RING) * SLOTF];
        const float* s2 = &ring[((q0 + 2) % RING) * SLOTF];

        f32x16 acc[2][2];
#pragma unroll
        for (int n = 0; n < 2; ++n) {
            // per-kw base/stride in dwords: main [c][64]: 512*g2+px, stride 64;
            // halo [c][4]: 1024+32*g2+(px-64), stride 4
            int bb[3], st[3];
#pragma unroll
            for (int kw = 0; kw < 3; ++kw) {
                int px = 32 * n + l31 + kw;
                bool mh = (px < 64);
                bb[kw] = mh ? (512 * g2 + px) : (1024 + 32 * g2 + (px - 64));
                st[kw] = mh ? 64 : 4;
            }
#pragma unroll
            for (int kh = 0; kh < 3; ++kh) {
                const float* sl = (kh == 0) ? s0 : (kh == 1) ? s1 : s2;
#pragma unroll
                for (int kw = 0; kw < 3; ++kw) {
                    f16x8 F;
#pragma unroll
                    for (int e = 0; e < 8; ++e)
                        F[e] = (_Float16)sl[bb[kw] + e * st[kw]];
#pragma unroll
                    for (int m = 0; m < 2; ++m) {
                        if (kh == 0 && kw == 0)
                            acc[n][m] = __builtin_amdgcn_mfma_f32_32x32x16_f16(
                                wreg[0][m], F, cbias[m], 0, 0, 0);
                        else
                            acc[n][m] = __builtin_amdgcn_mfma_f32_32x32x16_f16(
                                wreg[kh * 3 + kw][m], F, acc[n][m], 0, 0, 0);
                    }
                }
            }
        }

        // epilogue: min over 64 cout -> tanh(tanh) -> store
        const int oh = R0 + 4 * t + wv;
#pragma unroll
        for (int n = 0; n < 2; ++n) {
            float mn = fminf(acc[n][0][0], acc[n][1][0]);
#pragma unroll
            for (int q = 1; q < 16; ++q)
                mn = min3f(acc[n][0][q], acc[n][1][q], mn);
            mn = fminf(mn, __shfl_xor(mn, 32));
            float t2 = tanh_fast(tanh_fast(mn));
            const int opx = base + 32 * n + l31;
            if (g2 == 0 && oh < OH && opx < OW)
                out[obase + (size_t)oh * OW + opx] = t2;
        }
    }
}

extern "C" void kernel_launch(void* const* d_in, const int* in_sizes, int n_in,
                              void* d_out, int out_size, void* d_ws, size_t ws_size,
                              hipStream_t stream) {
    const float* x    = (const float*)d_in[0];
    const float* w    = (const float*)d_in[1];
    const float* bias = (const float*)d_in[2];
    float* out = (float*)d_out;
    _Float16* wpk = (_Float16*)d_ws;   // 9216 fp16 = 18,432 B

    wpack_kernel<<<36, 256, 0, stream>>>(w, wpk);
    conv_gll_kernel<<<512, 256, 0, stream>>>(x, (const f16x8*)wpk, bias, out);
}